// Round 7
// baseline (193.659 us; speedup 1.0000x reference)
//
#include <hip/hip_runtime.h>
#include <hip/hip_bf16.h>
#include <math.h>

#define B_   2
#define L_   1024
#define DM   1024
#define DI   2048
#define NS   16
#define NPJ  33
#define XPW_STRIDE 64   // padded x_proj rows / xp row stride
#define NCH  64     // chunks
#define CHL  16     // chunk length
#define XPSK 16     // x_proj split-K chunks
#define XPZ4 32768  // floats4 per xproj partial slice (2048*64/4)

typedef __bf16 bf16x8 __attribute__((ext_vector_type(8)));
typedef float  f32x4  __attribute__((ext_vector_type(4)));

__device__ __forceinline__ unsigned short f2bf_rn(float x) {
    union { float f; unsigned u; } a; a.f = x;
    unsigned r = a.u + 0x7fffu + ((a.u >> 16) & 1u);
    return (unsigned short)(r >> 16);
}
__device__ __forceinline__ float bf2f(unsigned short h) {
    union { unsigned u; float f; } a; a.u = ((unsigned)h) << 16;
    return a.f;
}
__device__ __forceinline__ float sigmoidf_(float x) { return 1.f / (1.f + __expf(-x)); }
__device__ __forceinline__ float softplusf_(float x) {
    return x > 20.f ? x : log1pf(__expf(x));
}

#define GLDS(g, l) __builtin_amdgcn_global_load_lds( \
    (__attribute__((address_space(1))) void*)(g),    \
    (__attribute__((address_space(3))) void*)(l), 16, 0, 0)

// ---------------- fused cast: x, w1, w2, padded x_proj_w -> hi/lo bf16 ----------------
#define XN4   524288          // 2048*1024/4
#define W1N4  1048576         // 4096*1024/4
#define W2N4  524288          // 1024*2048/4
#define WPN4  32768           // 64*2048/4
__global__ __launch_bounds__(256) void cast_all_kernel(
    const float* __restrict__ x, const float* __restrict__ w1,
    const float* __restrict__ w2, const float* __restrict__ xpw,
    unsigned short* __restrict__ xh, unsigned short* __restrict__ xl,
    unsigned short* __restrict__ w1h, unsigned short* __restrict__ w1l,
    unsigned short* __restrict__ w2h, unsigned short* __restrict__ w2l,
    unsigned short* __restrict__ wph, unsigned short* __restrict__ wpl)
{
    int i = blockIdx.x * 256 + threadIdx.x;
    float4 v;
    ushort4 *dh, *dl;
    int li;
    if (i < XN4) {
        li = i; v = ((const float4*)x)[li];
        dh = (ushort4*)xh; dl = (ushort4*)xl;
    } else if (i < XN4 + W1N4) {
        li = i - XN4; v = ((const float4*)w1)[li];
        dh = (ushort4*)w1h; dl = (ushort4*)w1l;
    } else if (i < XN4 + W1N4 + W2N4) {
        li = i - (XN4 + W1N4); v = ((const float4*)w2)[li];
        dh = (ushort4*)w2h; dl = (ushort4*)w2l;
    } else if (i < XN4 + W1N4 + W2N4 + WPN4) {
        li = i - (XN4 + W1N4 + W2N4);
        int j = li >> 9;
        v = (j < NPJ) ? ((const float4*)xpw)[li] : make_float4(0.f, 0.f, 0.f, 0.f);
        dh = (ushort4*)wph; dl = (ushort4*)wpl;
    } else return;
    ushort4 H, L;
    H.x = f2bf_rn(v.x); L.x = f2bf_rn(v.x - bf2f(H.x));
    H.y = f2bf_rn(v.y); L.y = f2bf_rn(v.y - bf2f(H.y));
    H.z = f2bf_rn(v.z); L.z = f2bf_rn(v.z - bf2f(H.z));
    H.w = f2bf_rn(v.w); L.w = f2bf_rn(v.w - bf2f(H.w));
    dh[li] = H; dl[li] = L;
}

// ---------------- split-bf16 GEMM: C[m][n] = sum_k A[m][k]*B[n][k] ----------------
// AL=true: 3-term (Ah*Bh + Ah*Bl + Al*Bh). AL=false: 2-term (Ah*Bh + Ah*Bl), Al unused.
// Split-K: gridDim.z chunks of KC; partial z written to C + z*M*N.
// NOTE: no XCD swizzle — R6 measured it raising FETCH 41->70MB for fat-N shapes.
template<int BM, int BN, bool AL>
__global__ __launch_bounds__(256) void gemm3_bt(
    const unsigned short* __restrict__ Ah, const unsigned short* __restrict__ Al,
    const unsigned short* __restrict__ Bh, const unsigned short* __restrict__ Bl,
    float* __restrict__ C, int M, int N, int K, int KC)
{
    constexpr int BK = 64;                 // 128 bytes per LDS row
    constexpr int FM = BM / 32;
    constexpr int FN = BN / 32;
    __shared__ alignas(16) char sAh[BM * BK * 2];
    __shared__ alignas(16) char sAl[AL ? BM * BK * 2 : 16];
    __shared__ alignas(16) char sBh[BN * BK * 2];
    __shared__ alignas(16) char sBl[BN * BK * 2];

    const int tid  = threadIdx.x;
    const int lane = tid & 63;
    const int wave = tid >> 6;
    const int wm = wave >> 1, wn = wave & 1;
    const int m0 = blockIdx.y * BM, n0 = blockIdx.x * BN;
    const int k0 = blockIdx.z * KC;

    f32x4 acc[FM][FN];
#pragma unroll
    for (int i = 0; i < FM; ++i)
#pragma unroll
        for (int j = 0; j < FN; ++j)
            acc[i][j] = (f32x4){0.f, 0.f, 0.f, 0.f};

    for (int kt = k0; kt < k0 + KC; kt += BK) {
#pragma unroll
        for (int iss = 0; iss < BM / 32; ++iss) {
            int o  = (iss * 256 + tid) * 16;
            int r  = o >> 7;
            int cb = (o & 127) ^ ((r & 7) << 4);
            size_t goff = (size_t)(m0 + r) * K + kt + (cb >> 1);
            GLDS(Ah + goff, sAh + iss * 4096 + wave * 1024);
            if (AL) GLDS(Al + goff, sAl + iss * 4096 + wave * 1024);
        }
#pragma unroll
        for (int iss = 0; iss < BN / 32; ++iss) {
            int o  = (iss * 256 + tid) * 16;
            int r  = o >> 7;
            int cb = (o & 127) ^ ((r & 7) << 4);
            size_t goff = (size_t)(n0 + r) * K + kt + (cb >> 1);
            GLDS(Bh + goff, sBh + iss * 4096 + wave * 1024);
            GLDS(Bl + goff, sBl + iss * 4096 + wave * 1024);
        }
        __syncthreads();

#pragma unroll
        for (int kk = 0; kk < 2; ++kk) {
            const int ke = kk * 32 + (lane >> 4) * 8;
            bf16x8 ah[FM], al[FM], bh[FN], bl[FN];
#pragma unroll
            for (int i = 0; i < FM; ++i) {
                int r = wm * (BM / 2) + i * 16 + (lane & 15);
                int off = (r * 128 + ke * 2) ^ ((r & 7) << 4);
                ah[i] = *(const bf16x8*)(sAh + off);
                if (AL) al[i] = *(const bf16x8*)(sAl + off);
            }
#pragma unroll
            for (int j = 0; j < FN; ++j) {
                int r = wn * (BN / 2) + j * 16 + (lane & 15);
                int off = (r * 128 + ke * 2) ^ ((r & 7) << 4);
                bh[j] = *(const bf16x8*)(sBh + off);
                bl[j] = *(const bf16x8*)(sBl + off);
            }
#pragma unroll
            for (int i = 0; i < FM; ++i)
#pragma unroll
                for (int j = 0; j < FN; ++j) {
                    acc[i][j] = __builtin_amdgcn_mfma_f32_16x16x32_bf16(ah[i], bh[j], acc[i][j], 0, 0, 0);
                    acc[i][j] = __builtin_amdgcn_mfma_f32_16x16x32_bf16(ah[i], bl[j], acc[i][j], 0, 0, 0);
                    if (AL) acc[i][j] = __builtin_amdgcn_mfma_f32_16x16x32_bf16(al[i], bh[j], acc[i][j], 0, 0, 0);
                }
        }
        __syncthreads();
    }

    float* Cz = C + (size_t)blockIdx.z * M * N;
#pragma unroll
    for (int i = 0; i < FM; ++i)
#pragma unroll
        for (int j = 0; j < FN; ++j) {
            int row = m0 + wm * (BM / 2) + i * 16 + (lane >> 4) * 4;
            int col = n0 + wn * (BN / 2) + j * 16 + (lane & 15);
            float* p = Cz + (size_t)row * N + col;
#pragma unroll
            for (int q = 0; q < 4; ++q) p[(size_t)q * N] = acc[i][j][q];
        }
}

// ---------------- reduce 4 split-K partials ----------------
__global__ __launch_bounds__(256) void reduce4_kernel(
    const float* __restrict__ part, float* __restrict__ out, int n4, int stride4)
{
    int i = blockIdx.x * 256 + threadIdx.x;
    if (i >= n4) return;
    const float4* p = (const float4*)part;
    float4 s = p[i];
#pragma unroll
    for (int z = 1; z < 4; ++z) {
        float4 v = p[(size_t)z * stride4 + i];
        s.x += v.x; s.y += v.y; s.z += v.z; s.w += v.w;
    }
    ((float4*)out)[i] = s;
}

// ---------------- x_proj split-K GEMM: part[z][m][n] = sum_{k in chunk z} xc[m][k]*Wp[n][k] ----------------
// SK=16 chunks of KC=128 -> 512 blocks (2/CU). Partials land in d_out (scratch window).
__global__ __launch_bounds__(256) void gemm3_xproj(
    const unsigned short* __restrict__ Ah, const unsigned short* __restrict__ Al,
    const unsigned short* __restrict__ Bh, const unsigned short* __restrict__ Bl,
    float* __restrict__ part)
{
    constexpr int BM = 64, BN = 64, BK = 64, KTOT = 2048, KC = 128;
    __shared__ alignas(16) char sAh[BM * 128];
    __shared__ alignas(16) char sAl[BM * 128];
    __shared__ alignas(16) char sBh[BN * 128];
    __shared__ alignas(16) char sBl[BN * 128];

    const int tid  = threadIdx.x;
    const int lane = tid & 63;
    const int wave = tid >> 6;
    const int wm = wave >> 1, wn = wave & 1;
    const int m0 = blockIdx.y * BM;
    const int kt0 = blockIdx.z * KC;

    f32x4 acc[2][2];
#pragma unroll
    for (int i = 0; i < 2; ++i)
#pragma unroll
        for (int j = 0; j < 2; ++j) acc[i][j] = (f32x4){0.f, 0.f, 0.f, 0.f};

    for (int kt = 0; kt < KC; kt += BK) {
#pragma unroll
        for (int iss = 0; iss < 2; ++iss) {
            int o  = (iss * 256 + tid) * 16;
            int r  = o >> 7;
            int cb = (o & 127) ^ ((r & 7) << 4);
            size_t ga = (size_t)(m0 + r) * KTOT + kt0 + kt + (cb >> 1);
            GLDS(Ah + ga, sAh + iss * 4096 + wave * 1024);
            GLDS(Al + ga, sAl + iss * 4096 + wave * 1024);
            size_t gb = (size_t)r * KTOT + kt0 + kt + (cb >> 1);
            GLDS(Bh + gb, sBh + iss * 4096 + wave * 1024);
            GLDS(Bl + gb, sBl + iss * 4096 + wave * 1024);
        }
        __syncthreads();

#pragma unroll
        for (int kk = 0; kk < 2; ++kk) {
            const int ke = kk * 32 + (lane >> 4) * 8;
            bf16x8 ah[2], al[2], bh[2], bl[2];
#pragma unroll
            for (int i = 0; i < 2; ++i) {
                int r = wm * 32 + i * 16 + (lane & 15);
                int off = (r * 128 + ke * 2) ^ ((r & 7) << 4);
                ah[i] = *(const bf16x8*)(sAh + off);
                al[i] = *(const bf16x8*)(sAl + off);
            }
#pragma unroll
            for (int j = 0; j < 2; ++j) {
                int r = wn * 32 + j * 16 + (lane & 15);
                int off = (r * 128 + ke * 2) ^ ((r & 7) << 4);
                bh[j] = *(const bf16x8*)(sBh + off);
                bl[j] = *(const bf16x8*)(sBl + off);
            }
#pragma unroll
            for (int i = 0; i < 2; ++i)
#pragma unroll
                for (int j = 0; j < 2; ++j) {
                    acc[i][j] = __builtin_amdgcn_mfma_f32_16x16x32_bf16(ah[i], bh[j], acc[i][j], 0, 0, 0);
                    acc[i][j] = __builtin_amdgcn_mfma_f32_16x16x32_bf16(ah[i], bl[j], acc[i][j], 0, 0, 0);
                    acc[i][j] = __builtin_amdgcn_mfma_f32_16x16x32_bf16(al[i], bh[j], acc[i][j], 0, 0, 0);
                }
        }
        __syncthreads();
    }

    float* Cp = part + (size_t)blockIdx.z * 2048 * XPW_STRIDE;
#pragma unroll
    for (int i = 0; i < 2; ++i)
#pragma unroll
        for (int j = 0; j < 2; ++j) {
            int row = m0 + wm * 32 + i * 16 + (lane >> 4) * 4;
            int col = wn * 32 + j * 16 + (lane & 15);
            float* p = Cp + (size_t)row * XPW_STRIDE + col;
#pragma unroll
            for (int q = 0; q < 4; ++q) p[(size_t)q * XPW_STRIDE] = acc[i][j][q];
        }
}

// ---------------- causal conv(4) + silu -> hi/lo bf16 ----------------
__global__ __launch_bounds__(256) void conv_silu_kernel(
    const float* __restrict__ xz, const float* __restrict__ cw,
    const float* __restrict__ cb, unsigned short* __restrict__ xch,
    unsigned short* __restrict__ xcl)
{
    int gid = blockIdx.x * 256 + threadIdx.x;   // 2048 rows * 512 vec4
    int m  = gid >> 9;
    int dv = (gid & 511) << 2;
    int t  = m & (L_ - 1);
    const float* base = xz + (size_t)m * (2 * DI) + dv;
    float4 s  = *(const float4*)(cb + dv);
    float4 w0 = *(const float4*)(cw + (dv + 0) * 4);
    float4 w1 = *(const float4*)(cw + (dv + 1) * 4);
    float4 w2 = *(const float4*)(cw + (dv + 2) * 4);
    float4 w3 = *(const float4*)(cw + (dv + 3) * 4);
    float4 z4 = make_float4(0.f, 0.f, 0.f, 0.f);
    float4 x3 = *(const float4*)(base);
    float4 x2 = (t >= 1) ? *(const float4*)(base - 1 * (2 * DI)) : z4;
    float4 x1 = (t >= 2) ? *(const float4*)(base - 2 * (2 * DI)) : z4;
    float4 x0 = (t >= 3) ? *(const float4*)(base - 3 * (2 * DI)) : z4;
    float r0 = s.x + w0.x * x0.x + w0.y * x1.x + w0.z * x2.x + w0.w * x3.x;
    float r1 = s.y + w1.x * x0.y + w1.y * x1.y + w1.z * x2.y + w1.w * x3.y;
    float r2 = s.z + w2.x * x0.z + w2.y * x1.z + w2.z * x2.z + w2.w * x3.z;
    float r3 = s.w + w3.x * x0.w + w3.y * x1.w + w3.z * x2.w + w3.w * x3.w;
    float4 o;
    o.x = r0 * sigmoidf_(r0);
    o.y = r1 * sigmoidf_(r1);
    o.z = r2 * sigmoidf_(r2);
    o.w = r3 * sigmoidf_(r3);
    ushort4 H, L;
    H.x = f2bf_rn(o.x); L.x = f2bf_rn(o.x - bf2f(H.x));
    H.y = f2bf_rn(o.y); L.y = f2bf_rn(o.y - bf2f(H.y));
    H.z = f2bf_rn(o.z); L.z = f2bf_rn(o.z - bf2f(H.z));
    H.w = f2bf_rn(o.w); L.w = f2bf_rn(o.w - bf2f(H.w));
    *(ushort4*)(xch + (size_t)m * DI + dv) = H;
    *(ushort4*)(xcl + (size_t)m * DI + dv) = L;
}

// ---------------- staged sum of 16 xproj partials into LDS ----------------
__device__ __forceinline__ void stage_sxp(
    float* sxp, const float* __restrict__ xp_part, int b, int c, int tid)
{
    const float4* base = (const float4*)(xp_part + (size_t)(b * L_ + c * CHL) * XPW_STRIDE);
    for (int i = tid; i < CHL * XPW_STRIDE / 4; i += 256) {
        float4 s = base[i];
#pragma unroll
        for (int z = 1; z < XPSK; ++z) {
            float4 v = base[(size_t)z * XPZ4 + i];
            s.x += v.x; s.y += v.y; s.z += v.z; s.w += v.w;
        }
        ((float4*)sxp)[i] = s;
    }
    __syncthreads();
}

// ---------------- scan pass 1: per-chunk local scan (h_in = 0) + sum(dt) ----------------
__global__ __launch_bounds__(256) void scan_pass1(
    const unsigned short* __restrict__ xch, const unsigned short* __restrict__ xcl,
    const float* __restrict__ xp_part,
    const float* __restrict__ dtw, const float* __restrict__ dtb,
    const float* __restrict__ A_log, float* __restrict__ h0, float* __restrict__ sumdt)
{
    const int b = blockIdx.z, c = blockIdx.y;
    const int tid = threadIdx.x;
    const int d = blockIdx.x * 256 + tid;
    __shared__ float sxp[CHL * XPW_STRIDE];
    stage_sxp(sxp, xp_part, b, c, tid);

    float Av[NS];
#pragma unroll
    for (int n = 0; n < NS; ++n) Av[n] = -__expf(A_log[(size_t)d * NS + n]);
    const float w = dtw[d], bb = dtb[d];
    float h[NS];
#pragma unroll
    for (int n = 0; n < NS; ++n) h[n] = 0.f;
    float sd = 0.f;
    size_t off = (size_t)(b * L_ + c * CHL) * DI + d;

    unsigned short nh = xch[off], nl = xcl[off];
    for (int t = 0; t < CHL; ++t) {
        unsigned short ch = nh, cl = nl;
        nh = xch[off + DI]; nl = xcl[off + DI];    // prefetch t+1 (last iter overruns, value unused)
        off += DI;
        float xcv = bf2f(ch) + bf2f(cl);
        float dt  = softplusf_(fmaf(sxp[t * XPW_STRIDE], w, bb));
        sd += dt;
        float u = dt * xcv;
#pragma unroll
        for (int n = 0; n < NS; ++n) {
            float a = __expf(dt * Av[n]);
            h[n] = fmaf(a, h[n], u * sxp[t * XPW_STRIDE + 1 + n]);
        }
    }
    float* hp = h0 + ((size_t)(b * NCH + c) * DI + d) * NS;
#pragma unroll
    for (int n = 0; n < NS; n += 4)
        *(float4*)(hp + n) = make_float4(h[n], h[n + 1], h[n + 2], h[n + 3]);
    sumdt[(size_t)(b * NCH + c) * DI + d] = sd;
}

// ---------------- scan pass 2: chunk-level prefix (in place: h0 becomes h_in) ----------------
// Batched: 16 independent loads + exps per group, serial chain is fma-only.
__global__ __launch_bounds__(256) void scan_pass2(
    const float* __restrict__ A_log, const float* __restrict__ sumdt, float* __restrict__ h0)
{
    int gid = blockIdx.x * 256 + threadIdx.x;   // B_*DI*NS = 65536
    int b = gid >> 15;
    int r = gid & 32767;
    int d = r >> 4, n = r & 15;
    float An = -__expf(A_log[(size_t)d * NS + n]);
    float h = 0.f;
    for (int cb = 0; cb < NCH; cb += 16) {
        float hl[16], e[16];
#pragma unroll
        for (int j = 0; j < 16; ++j) {
            size_t ci = (size_t)(b * NCH + cb + j) * DI + d;
            hl[j] = h0[ci * NS + n];
            e[j]  = An * sumdt[ci];
        }
#pragma unroll
        for (int j = 0; j < 16; ++j) e[j] = __expf(e[j]);
#pragma unroll
        for (int j = 0; j < 16; ++j) {
            size_t ci = (size_t)(b * NCH + cb + j) * DI + d;
            h0[ci * NS + n] = h;
            h = fmaf(e[j], h, hl[j]);
        }
    }
}

// ---------------- scan pass 3: replay with h_in, fuse y, D-skip, silu(z), bf16 ----------------
__global__ __launch_bounds__(256) void scan_pass3(
    const unsigned short* __restrict__ xch, const unsigned short* __restrict__ xcl,
    const float* __restrict__ xp_part, const float* __restrict__ xz,
    const float* __restrict__ dtw, const float* __restrict__ dtb,
    const float* __restrict__ A_log, const float* __restrict__ Dp,
    const float* __restrict__ hin,
    unsigned short* __restrict__ yh)
{
    const int b = blockIdx.z, c = blockIdx.y;
    const int tid = threadIdx.x;
    const int d = blockIdx.x * 256 + tid;
    __shared__ float sxp[CHL * XPW_STRIDE];
    stage_sxp(sxp, xp_part, b, c, tid);

    float Av[NS];
#pragma unroll
    for (int n = 0; n < NS; ++n) Av[n] = -__expf(A_log[(size_t)d * NS + n]);
    const float w = dtw[d], bb = dtb[d], Dv = Dp[d];
    float h[NS];
    const float* hp = hin + ((size_t)(b * NCH + c) * DI + d) * NS;
#pragma unroll
    for (int n = 0; n < NS; n += 4) {
        float4 v = *(const float4*)(hp + n);
        h[n] = v.x; h[n + 1] = v.y; h[n + 2] = v.z; h[n + 3] = v.w;
    }
    size_t off = (size_t)(b * L_ + c * CHL) * DI + d;
    const float* zp  = xz + (size_t)(b * L_ + c * CHL) * (2 * DI) + DI + d;
    unsigned short* yhp = yh + off;

    unsigned short nh = xch[off], nl = xcl[off];
    float nz = zp[0];
    for (int t = 0; t < CHL; ++t) {
        unsigned short ch = nh, cl = nl;
        float zv = nz;
        nh = xch[off + DI]; nl = xcl[off + DI];            // prefetch (overrun on last iter, unused)
        nz = zp[(size_t)(t + 1) * (2 * DI)];
        off += DI;
        float xcv = bf2f(ch) + bf2f(cl);
        float dt  = softplusf_(fmaf(sxp[t * XPW_STRIDE], w, bb));
        float u = dt * xcv;
        float y = 0.f;
#pragma unroll
        for (int n = 0; n < NS; ++n) {
            float a = __expf(dt * Av[n]);
            h[n] = fmaf(a, h[n], u * sxp[t * XPW_STRIDE + 1 + n]);
            y = fmaf(h[n], sxp[t * XPW_STRIDE + 17 + n], y);
        }
        float out = fmaf(xcv, Dv, y) * (zv * sigmoidf_(zv));
        yhp[(size_t)t * DI] = f2bf_rn(out);
    }
}

extern "C" void kernel_launch(void* const* d_in, const int* in_sizes, int n_in,
                              void* d_out, int out_size, void* d_ws, size_t ws_size,
                              hipStream_t stream)
{
    (void)in_sizes; (void)n_in; (void)out_size;
    const float* x    = (const float*)d_in[0];
    const float* w1   = (const float*)d_in[1];
    const float* cw   = (const float*)d_in[2];
    const float* cb   = (const float*)d_in[3];
    const float* xpw  = (const float*)d_in[4];
    const float* dtw  = (const float*)d_in[5];
    const float* dtb  = (const float*)d_in[6];
    const float* alog = (const float*)d_in[7];
    const float* Dp   = (const float*)d_in[8];
    const float* w2   = (const float*)d_in[9];
    float* out = (float*)d_out;

    char* ws = (char*)d_ws;
    const size_t MB = 1024 * 1024;
    const size_t KB = 1024;
    if (ws_size < 81 * MB) return;

    // phase-1 overlay [0, 24MB): cast inputs for GEMM1
    unsigned short* x_hi  = (unsigned short*)(ws + 0);        // 4 MB
    unsigned short* x_lo  = (unsigned short*)(ws + 4 * MB);   // 4 MB
    unsigned short* w1_hi = (unsigned short*)(ws + 8 * MB);   // 8 MB
    unsigned short* w1_lo = (unsigned short*)(ws + 16 * MB);  // 8 MB
    // scan-phase overlay ([0,24MB) free: x/w1 dead after GEMM1):
    float* sumdt = (float*)(ws + 0);                          // 1 MB (dead before y_hi write: pass1 w, pass2 r)
    unsigned short* y_hi  = (unsigned short*)(ws + 0);        // 8 MB (pass3 write overwrites sumdt - OK, dead)
    float* h0    = (float*)(ws + 8 * MB);                     // 16 MB (2*64*2048*16 f32)
    // xproj partials: d_out as scratch (8 MB; overwritten by reduce4 at the end)
    float* xp_part = (float*)d_out;                           // 16 x 2048 x 64 f32 = 8 MB
    // fixed region:
    float* xz = (float*)(ws + 24 * MB);                       // 32 MB
    float* c_part = (float*)(ws + 24 * MB);                   // 32 MB (GEMM2 split-K partials; xz dead by then)
    unsigned short* xc_hi = (unsigned short*)(ws + 56 * MB);  // 8 MB
    unsigned short* xc_lo = (unsigned short*)(ws + 64 * MB);  // 8 MB
    unsigned short* wp_hi = (unsigned short*)(ws + 72 * MB);             // 256 KB
    unsigned short* wp_lo = (unsigned short*)(ws + 72 * MB + 256 * KB);  // 256 KB
    unsigned short* w2_hi = (unsigned short*)(ws + 73 * MB);  // 4 MB
    unsigned short* w2_lo = (unsigned short*)(ws + 77 * MB);  // 4 MB

    // fused casts (x, w1, w2, padded x_proj_w)
    {
        int total = XN4 + W1N4 + W2N4 + WPN4;
        cast_all_kernel<<<(total + 255) / 256, 256, 0, stream>>>(
            x, w1, w2, xpw, x_hi, x_lo, w1_hi, w1_lo, w2_hi, w2_lo, wp_hi, wp_lo);
    }

    // GEMM1 (3-term): xz[2048][4096] = x[2048][1024] . in_proj_w[4096][1024]^T
    {
        dim3 g(4096 / 128, 2048 / 128, 1);
        gemm3_bt<128, 128, true><<<g, 256, 0, stream>>>(x_hi, x_lo, w1_hi, w1_lo, xz, 2048, 4096, 1024, 1024);
    }

    conv_silu_kernel<<<(2048 * 512) / 256, 256, 0, stream>>>(xz, cw, cb, xc_hi, xc_lo);

    // x_proj via split-K MFMA GEMM (M=2048, N=64 padded, K=2048, SK=16) -> partials in d_out
    {
        dim3 g(1, 2048 / 64, XPSK);
        gemm3_xproj<<<g, 256, 0, stream>>>(xc_hi, xc_lo, wp_hi, wp_lo, xp_part);
    }

    {
        dim3 gs(DI / 256, NCH, B_);
        scan_pass1<<<gs, 256, 0, stream>>>(xc_hi, xc_lo, xp_part, dtw, dtb, alog, h0, sumdt);
        scan_pass2<<<(B_ * DI * NS) / 256, 256, 0, stream>>>(alog, sumdt, h0);
        scan_pass3<<<gs, 256, 0, stream>>>(xc_hi, xc_lo, xp_part, xz, dtw, dtb, alog, Dp, h0, y_hi);
    }

    // GEMM2 (2-term, y bf16-hi only): out[2048][1024] = y[2048][2048] . out_proj_w[1024][2048]^T
    // split-K=4 (KC=512) -> 512 blocks (2/CU), fp32 partials in c_part, then reduce.
    {
        dim3 g(1024 / 128, 2048 / 128, 4);
        gemm3_bt<128, 128, false><<<g, 256, 0, stream>>>(y_hi, nullptr, w2_hi, w2_lo, c_part, 2048, 1024, 2048, 512);
        reduce4_kernel<<<(2048 * 1024 / 4 + 255) / 256, 256, 0, stream>>>(c_part, out, 2048 * 1024 / 4, 2048 * 1024 / 4);
    }
}

// Round 8
// 184.713 us; speedup vs baseline: 1.0484x; 1.0484x over previous
//
#include <hip/hip_runtime.h>
#include <hip/hip_bf16.h>
#include <math.h>

#define B_   2
#define L_   1024
#define DM   1024
#define DI   2048
#define NS   16
#define NPJ  33
#define XPW_STRIDE 64   // padded x_proj rows / xp row stride
#define NCH  64     // chunks
#define CHL  16     // chunk length

typedef __bf16 bf16x8 __attribute__((ext_vector_type(8)));
typedef float  f32x4  __attribute__((ext_vector_type(4)));

__device__ __forceinline__ unsigned short f2bf_rn(float x) {
    union { float f; unsigned u; } a; a.f = x;
    unsigned r = a.u + 0x7fffu + ((a.u >> 16) & 1u);
    return (unsigned short)(r >> 16);
}
__device__ __forceinline__ float bf2f(unsigned short h) {
    union { unsigned u; float f; } a; a.u = ((unsigned)h) << 16;
    return a.f;
}
__device__ __forceinline__ float sigmoidf_(float x) { return 1.f / (1.f + __expf(-x)); }
__device__ __forceinline__ float softplusf_(float x) {
    return x > 20.f ? x : log1pf(__expf(x));
}

#define GLDS(g, l) __builtin_amdgcn_global_load_lds( \
    (__attribute__((address_space(1))) void*)(g),    \
    (__attribute__((address_space(3))) void*)(l), 16, 0, 0)

// ---------------- fused cast: x, w1, w2, padded x_proj_w -> hi/lo bf16 ----------------
#define XN4   524288          // 2048*1024/4
#define W1N4  1048576         // 4096*1024/4
#define W2N4  524288          // 1024*2048/4
#define WPN4  32768           // 64*2048/4
__global__ __launch_bounds__(256) void cast_all_kernel(
    const float* __restrict__ x, const float* __restrict__ w1,
    const float* __restrict__ w2, const float* __restrict__ xpw,
    unsigned short* __restrict__ xh, unsigned short* __restrict__ xl,
    unsigned short* __restrict__ w1h, unsigned short* __restrict__ w1l,
    unsigned short* __restrict__ w2h, unsigned short* __restrict__ w2l,
    unsigned short* __restrict__ wph, unsigned short* __restrict__ wpl)
{
    int i = blockIdx.x * 256 + threadIdx.x;
    float4 v;
    ushort4 *dh, *dl;
    int li;
    if (i < XN4) {
        li = i; v = ((const float4*)x)[li];
        dh = (ushort4*)xh; dl = (ushort4*)xl;
    } else if (i < XN4 + W1N4) {
        li = i - XN4; v = ((const float4*)w1)[li];
        dh = (ushort4*)w1h; dl = (ushort4*)w1l;
    } else if (i < XN4 + W1N4 + W2N4) {
        li = i - (XN4 + W1N4); v = ((const float4*)w2)[li];
        dh = (ushort4*)w2h; dl = (ushort4*)w2l;
    } else if (i < XN4 + W1N4 + W2N4 + WPN4) {
        li = i - (XN4 + W1N4 + W2N4);
        int j = li >> 9;
        v = (j < NPJ) ? ((const float4*)xpw)[li] : make_float4(0.f, 0.f, 0.f, 0.f);
        dh = (ushort4*)wph; dl = (ushort4*)wpl;
    } else return;
    ushort4 H, L;
    H.x = f2bf_rn(v.x); L.x = f2bf_rn(v.x - bf2f(H.x));
    H.y = f2bf_rn(v.y); L.y = f2bf_rn(v.y - bf2f(H.y));
    H.z = f2bf_rn(v.z); L.z = f2bf_rn(v.z - bf2f(H.z));
    H.w = f2bf_rn(v.w); L.w = f2bf_rn(v.w - bf2f(H.w));
    dh[li] = H; dl[li] = L;
}

// ---------------- split-bf16 GEMM: C[m][n] = sum_k A[m][k]*B[n][k] ----------------
// Terms: Ah*Bh + Ah*Bl always; + Al*Bh for blocks with n0 >= n3_start (when AL).
// (Mixed precision: x_ssm half 2-term [errors sqrt(K)-averaged downstream],
//  z half 3-term [gate multiplies y at full magnitude].)
// Split-K: gridDim.z chunks of KC; partial z written to C + z*M*N.
// NOTE: no XCD swizzle — R6 measured it raising FETCH 41->70MB for fat-N shapes.
template<int BM, int BN, bool AL>
__global__ __launch_bounds__(256) void gemm3_bt(
    const unsigned short* __restrict__ Ah, const unsigned short* __restrict__ Al,
    const unsigned short* __restrict__ Bh, const unsigned short* __restrict__ Bl,
    float* __restrict__ C, int M, int N, int K, int KC, int n3_start)
{
    constexpr int BK = 64;                 // 128 bytes per LDS row
    constexpr int FM = BM / 32;
    constexpr int FN = BN / 32;
    __shared__ alignas(16) char sAh[BM * BK * 2];
    __shared__ alignas(16) char sAl[AL ? BM * BK * 2 : 16];
    __shared__ alignas(16) char sBh[BN * BK * 2];
    __shared__ alignas(16) char sBl[BN * BK * 2];

    const int tid  = threadIdx.x;
    const int lane = tid & 63;
    const int wave = tid >> 6;
    const int wm = wave >> 1, wn = wave & 1;
    const int m0 = blockIdx.y * BM, n0 = blockIdx.x * BN;
    const int k0 = blockIdx.z * KC;
    const bool use3 = AL && (n0 >= n3_start);

    f32x4 acc[FM][FN];
#pragma unroll
    for (int i = 0; i < FM; ++i)
#pragma unroll
        for (int j = 0; j < FN; ++j)
            acc[i][j] = (f32x4){0.f, 0.f, 0.f, 0.f};

    for (int kt = k0; kt < k0 + KC; kt += BK) {
#pragma unroll
        for (int iss = 0; iss < BM / 32; ++iss) {
            int o  = (iss * 256 + tid) * 16;
            int r  = o >> 7;
            int cb = (o & 127) ^ ((r & 7) << 4);
            size_t goff = (size_t)(m0 + r) * K + kt + (cb >> 1);
            GLDS(Ah + goff, sAh + iss * 4096 + wave * 1024);
            if (use3) GLDS(Al + goff, sAl + iss * 4096 + wave * 1024);
        }
#pragma unroll
        for (int iss = 0; iss < BN / 32; ++iss) {
            int o  = (iss * 256 + tid) * 16;
            int r  = o >> 7;
            int cb = (o & 127) ^ ((r & 7) << 4);
            size_t goff = (size_t)(n0 + r) * K + kt + (cb >> 1);
            GLDS(Bh + goff, sBh + iss * 4096 + wave * 1024);
            GLDS(Bl + goff, sBl + iss * 4096 + wave * 1024);
        }
        __syncthreads();

#pragma unroll
        for (int kk = 0; kk < 2; ++kk) {
            const int ke = kk * 32 + (lane >> 4) * 8;
            bf16x8 ah[FM], al[FM], bh[FN], bl[FN];
#pragma unroll
            for (int i = 0; i < FM; ++i) {
                int r = wm * (BM / 2) + i * 16 + (lane & 15);
                int off = (r * 128 + ke * 2) ^ ((r & 7) << 4);
                ah[i] = *(const bf16x8*)(sAh + off);
                if (use3) al[i] = *(const bf16x8*)(sAl + off);
            }
#pragma unroll
            for (int j = 0; j < FN; ++j) {
                int r = wn * (BN / 2) + j * 16 + (lane & 15);
                int off = (r * 128 + ke * 2) ^ ((r & 7) << 4);
                bh[j] = *(const bf16x8*)(sBh + off);
                bl[j] = *(const bf16x8*)(sBl + off);
            }
#pragma unroll
            for (int i = 0; i < FM; ++i)
#pragma unroll
                for (int j = 0; j < FN; ++j) {
                    acc[i][j] = __builtin_amdgcn_mfma_f32_16x16x32_bf16(ah[i], bh[j], acc[i][j], 0, 0, 0);
                    acc[i][j] = __builtin_amdgcn_mfma_f32_16x16x32_bf16(ah[i], bl[j], acc[i][j], 0, 0, 0);
                    if (use3) acc[i][j] = __builtin_amdgcn_mfma_f32_16x16x32_bf16(al[i], bh[j], acc[i][j], 0, 0, 0);
                }
        }
        __syncthreads();
    }

    float* Cz = C + (size_t)blockIdx.z * M * N;
#pragma unroll
    for (int i = 0; i < FM; ++i)
#pragma unroll
        for (int j = 0; j < FN; ++j) {
            int row = m0 + wm * (BM / 2) + i * 16 + (lane >> 4) * 4;
            int col = n0 + wn * (BN / 2) + j * 16 + (lane & 15);
            float* p = Cz + (size_t)row * N + col;
#pragma unroll
            for (int q = 0; q < 4; ++q) p[(size_t)q * N] = acc[i][j][q];
        }
}

// ---------------- reduce 4 split-K partials ----------------
__global__ __launch_bounds__(256) void reduce4_kernel(
    const float* __restrict__ part, float* __restrict__ out, int n4, int stride4)
{
    int i = blockIdx.x * 256 + threadIdx.x;
    if (i >= n4) return;
    const float4* p = (const float4*)part;
    float4 s = p[i];
#pragma unroll
    for (int z = 1; z < 4; ++z) {
        float4 v = p[(size_t)z * stride4 + i];
        s.x += v.x; s.y += v.y; s.z += v.z; s.w += v.w;
    }
    ((float4*)out)[i] = s;
}

// ---------------- x_proj split-K GEMM: part[z][m][n] = sum_{k in chunk z} xc[m][k]*Wp[n][k] ----------------
__global__ __launch_bounds__(256) void gemm3_xproj(
    const unsigned short* __restrict__ Ah, const unsigned short* __restrict__ Al,
    const unsigned short* __restrict__ Bh, const unsigned short* __restrict__ Bl,
    float* __restrict__ part)
{
    constexpr int BM = 64, BN = 64, BK = 64, KTOT = 2048, KC = 256;
    __shared__ alignas(16) char sAh[BM * 128];
    __shared__ alignas(16) char sAl[BM * 128];
    __shared__ alignas(16) char sBh[BN * 128];
    __shared__ alignas(16) char sBl[BN * 128];

    const int tid  = threadIdx.x;
    const int lane = tid & 63;
    const int wave = tid >> 6;
    const int wm = wave >> 1, wn = wave & 1;
    const int m0 = blockIdx.y * BM;
    const int kt0 = blockIdx.z * KC;

    f32x4 acc[2][2];
#pragma unroll
    for (int i = 0; i < 2; ++i)
#pragma unroll
        for (int j = 0; j < 2; ++j) acc[i][j] = (f32x4){0.f, 0.f, 0.f, 0.f};

    for (int kt = 0; kt < KC; kt += BK) {
#pragma unroll
        for (int iss = 0; iss < 2; ++iss) {
            int o  = (iss * 256 + tid) * 16;
            int r  = o >> 7;
            int cb = (o & 127) ^ ((r & 7) << 4);
            size_t ga = (size_t)(m0 + r) * KTOT + kt0 + kt + (cb >> 1);
            GLDS(Ah + ga, sAh + iss * 4096 + wave * 1024);
            GLDS(Al + ga, sAl + iss * 4096 + wave * 1024);
            size_t gb = (size_t)r * KTOT + kt0 + kt + (cb >> 1);
            GLDS(Bh + gb, sBh + iss * 4096 + wave * 1024);
            GLDS(Bl + gb, sBl + iss * 4096 + wave * 1024);
        }
        __syncthreads();

#pragma unroll
        for (int kk = 0; kk < 2; ++kk) {
            const int ke = kk * 32 + (lane >> 4) * 8;
            bf16x8 ah[2], al[2], bh[2], bl[2];
#pragma unroll
            for (int i = 0; i < 2; ++i) {
                int r = wm * 32 + i * 16 + (lane & 15);
                int off = (r * 128 + ke * 2) ^ ((r & 7) << 4);
                ah[i] = *(const bf16x8*)(sAh + off);
                al[i] = *(const bf16x8*)(sAl + off);
            }
#pragma unroll
            for (int j = 0; j < 2; ++j) {
                int r = wn * 32 + j * 16 + (lane & 15);
                int off = (r * 128 + ke * 2) ^ ((r & 7) << 4);
                bh[j] = *(const bf16x8*)(sBh + off);
                bl[j] = *(const bf16x8*)(sBl + off);
            }
#pragma unroll
            for (int i = 0; i < 2; ++i)
#pragma unroll
                for (int j = 0; j < 2; ++j) {
                    acc[i][j] = __builtin_amdgcn_mfma_f32_16x16x32_bf16(ah[i], bh[j], acc[i][j], 0, 0, 0);
                    acc[i][j] = __builtin_amdgcn_mfma_f32_16x16x32_bf16(ah[i], bl[j], acc[i][j], 0, 0, 0);
                    acc[i][j] = __builtin_amdgcn_mfma_f32_16x16x32_bf16(al[i], bh[j], acc[i][j], 0, 0, 0);
                }
        }
        __syncthreads();
    }

    float* Cp = part + (size_t)blockIdx.z * 2048 * XPW_STRIDE;
#pragma unroll
    for (int i = 0; i < 2; ++i)
#pragma unroll
        for (int j = 0; j < 2; ++j) {
            int row = m0 + wm * 32 + i * 16 + (lane >> 4) * 4;
            int col = wn * 32 + j * 16 + (lane & 15);
            float* p = Cp + (size_t)row * XPW_STRIDE + col;
#pragma unroll
            for (int q = 0; q < 4; ++q) p[(size_t)q * XPW_STRIDE] = acc[i][j][q];
        }
}

// ---------------- reduce split-K partials: xp = sum_z part[z] ----------------
__global__ __launch_bounds__(256) void xproj_reduce(
    const float* __restrict__ part, float* __restrict__ xp)
{
    int i = blockIdx.x * 256 + threadIdx.x;   // over 2048*64/4 = 32768 float4
    const float4* p = (const float4*)part;
    float4 s = p[i];
#pragma unroll
    for (int z = 1; z < 8; ++z) {
        float4 v = p[(size_t)z * 32768 + i];
        s.x += v.x; s.y += v.y; s.z += v.z; s.w += v.w;
    }
    ((float4*)xp)[i] = s;
}

// ---------------- causal conv(4) + silu -> hi/lo bf16 ----------------
__global__ __launch_bounds__(256) void conv_silu_kernel(
    const float* __restrict__ xz, const float* __restrict__ cw,
    const float* __restrict__ cb, unsigned short* __restrict__ xch,
    unsigned short* __restrict__ xcl)
{
    int gid = blockIdx.x * 256 + threadIdx.x;   // 2048 rows * 512 vec4
    int m  = gid >> 9;
    int dv = (gid & 511) << 2;
    int t  = m & (L_ - 1);
    const float* base = xz + (size_t)m * (2 * DI) + dv;
    float4 s  = *(const float4*)(cb + dv);
    float4 w0 = *(const float4*)(cw + (dv + 0) * 4);
    float4 w1 = *(const float4*)(cw + (dv + 1) * 4);
    float4 w2 = *(const float4*)(cw + (dv + 2) * 4);
    float4 w3 = *(const float4*)(cw + (dv + 3) * 4);
    float4 z4 = make_float4(0.f, 0.f, 0.f, 0.f);
    float4 x3 = *(const float4*)(base);
    float4 x2 = (t >= 1) ? *(const float4*)(base - 1 * (2 * DI)) : z4;
    float4 x1 = (t >= 2) ? *(const float4*)(base - 2 * (2 * DI)) : z4;
    float4 x0 = (t >= 3) ? *(const float4*)(base - 3 * (2 * DI)) : z4;
    float r0 = s.x + w0.x * x0.x + w0.y * x1.x + w0.z * x2.x + w0.w * x3.x;
    float r1 = s.y + w1.x * x0.y + w1.y * x1.y + w1.z * x2.y + w1.w * x3.y;
    float r2 = s.z + w2.x * x0.z + w2.y * x1.z + w2.z * x2.z + w2.w * x3.z;
    float r3 = s.w + w3.x * x0.w + w3.y * x1.w + w3.z * x2.w + w3.w * x3.w;
    float4 o;
    o.x = r0 * sigmoidf_(r0);
    o.y = r1 * sigmoidf_(r1);
    o.z = r2 * sigmoidf_(r2);
    o.w = r3 * sigmoidf_(r3);
    ushort4 H, L;
    H.x = f2bf_rn(o.x); L.x = f2bf_rn(o.x - bf2f(H.x));
    H.y = f2bf_rn(o.y); L.y = f2bf_rn(o.y - bf2f(H.y));
    H.z = f2bf_rn(o.z); L.z = f2bf_rn(o.z - bf2f(H.z));
    H.w = f2bf_rn(o.w); L.w = f2bf_rn(o.w - bf2f(H.w));
    *(ushort4*)(xch + (size_t)m * DI + dv) = H;
    *(ushort4*)(xcl + (size_t)m * DI + dv) = L;
}

// ---------------- scan pass 1: per-chunk local scan (h_in = 0) + sum(dt) ----------------
__global__ __launch_bounds__(256) void scan_pass1(
    const unsigned short* __restrict__ xch, const unsigned short* __restrict__ xcl,
    const float* __restrict__ xp,
    const float* __restrict__ dtw, const float* __restrict__ dtb,
    const float* __restrict__ A_log, float* __restrict__ h0, float* __restrict__ sumdt)
{
    const int b = blockIdx.z, c = blockIdx.y;
    const int tid = threadIdx.x;
    const int d = blockIdx.x * 256 + tid;
    __shared__ float sxp[CHL * XPW_STRIDE];
    const float* xpsrc = xp + (size_t)(b * L_ + c * CHL) * XPW_STRIDE;
    for (int i = tid; i < CHL * XPW_STRIDE / 4; i += 256)
        ((float4*)sxp)[i] = ((const float4*)xpsrc)[i];
    __syncthreads();

    float Av[NS];
#pragma unroll
    for (int n = 0; n < NS; ++n) Av[n] = -__expf(A_log[(size_t)d * NS + n]);
    const float w = dtw[d], bb = dtb[d];
    float h[NS];
#pragma unroll
    for (int n = 0; n < NS; ++n) h[n] = 0.f;
    float sd = 0.f;
    size_t off = (size_t)(b * L_ + c * CHL) * DI + d;

    unsigned short nh = xch[off], nl = xcl[off];
    for (int t = 0; t < CHL; ++t) {
        unsigned short ch = nh, cl = nl;
        nh = xch[off + DI]; nl = xcl[off + DI];    // prefetch t+1 (last iter overruns, value unused)
        off += DI;
        float xcv = bf2f(ch) + bf2f(cl);
        float dt  = softplusf_(fmaf(sxp[t * XPW_STRIDE], w, bb));
        sd += dt;
        float u = dt * xcv;
#pragma unroll
        for (int n = 0; n < NS; ++n) {
            float a = __expf(dt * Av[n]);
            h[n] = fmaf(a, h[n], u * sxp[t * XPW_STRIDE + 1 + n]);
        }
    }
    float* hp = h0 + ((size_t)(b * NCH + c) * DI + d) * NS;
#pragma unroll
    for (int n = 0; n < NS; n += 4)
        *(float4*)(hp + n) = make_float4(h[n], h[n + 1], h[n + 2], h[n + 3]);
    sumdt[(size_t)(b * NCH + c) * DI + d] = sd;
}

// ---------------- scan pass 2: chunk-level prefix (in place: h0 becomes h_in) ----------------
// Batched: 16 independent loads + exps per group, serial chain is fma-only.
__global__ __launch_bounds__(256) void scan_pass2(
    const float* __restrict__ A_log, const float* __restrict__ sumdt, float* __restrict__ h0)
{
    int gid = blockIdx.x * 256 + threadIdx.x;   // B_*DI*NS = 65536
    int b = gid >> 15;
    int r = gid & 32767;
    int d = r >> 4, n = r & 15;
    float An = -__expf(A_log[(size_t)d * NS + n]);
    float h = 0.f;
    for (int cb = 0; cb < NCH; cb += 16) {
        float hl[16], e[16];
#pragma unroll
        for (int j = 0; j < 16; ++j) {
            size_t ci = (size_t)(b * NCH + cb + j) * DI + d;
            hl[j] = h0[ci * NS + n];
            e[j]  = An * sumdt[ci];
        }
#pragma unroll
        for (int j = 0; j < 16; ++j) e[j] = __expf(e[j]);
#pragma unroll
        for (int j = 0; j < 16; ++j) {
            size_t ci = (size_t)(b * NCH + cb + j) * DI + d;
            h0[ci * NS + n] = h;
            h = fmaf(e[j], h, hl[j]);
        }
    }
}

// ---------------- scan pass 3: replay with h_in, fuse y, D-skip, silu(z), bf16 ----------------
__global__ __launch_bounds__(256) void scan_pass3(
    const unsigned short* __restrict__ xch, const unsigned short* __restrict__ xcl,
    const float* __restrict__ xp, const float* __restrict__ xz,
    const float* __restrict__ dtw, const float* __restrict__ dtb,
    const float* __restrict__ A_log, const float* __restrict__ Dp,
    const float* __restrict__ hin,
    unsigned short* __restrict__ yh)
{
    const int b = blockIdx.z, c = blockIdx.y;
    const int tid = threadIdx.x;
    const int d = blockIdx.x * 256 + tid;
    __shared__ float sxp[CHL * XPW_STRIDE];
    const float* xpsrc = xp + (size_t)(b * L_ + c * CHL) * XPW_STRIDE;
    for (int i = tid; i < CHL * XPW_STRIDE / 4; i += 256)
        ((float4*)sxp)[i] = ((const float4*)xpsrc)[i];
    __syncthreads();

    float Av[NS];
#pragma unroll
    for (int n = 0; n < NS; ++n) Av[n] = -__expf(A_log[(size_t)d * NS + n]);
    const float w = dtw[d], bb = dtb[d], Dv = Dp[d];
    float h[NS];
    const float* hp = hin + ((size_t)(b * NCH + c) * DI + d) * NS;
#pragma unroll
    for (int n = 0; n < NS; n += 4) {
        float4 v = *(const float4*)(hp + n);
        h[n] = v.x; h[n + 1] = v.y; h[n + 2] = v.z; h[n + 3] = v.w;
    }
    size_t off = (size_t)(b * L_ + c * CHL) * DI + d;
    const float* zp  = xz + (size_t)(b * L_ + c * CHL) * (2 * DI) + DI + d;
    unsigned short* yhp = yh + off;

    unsigned short nh = xch[off], nl = xcl[off];
    float nz = zp[0];
    for (int t = 0; t < CHL; ++t) {
        unsigned short ch = nh, cl = nl;
        float zv = nz;
        nh = xch[off + DI]; nl = xcl[off + DI];            // prefetch (overrun on last iter, unused)
        nz = zp[(size_t)(t + 1) * (2 * DI)];
        off += DI;
        float xcv = bf2f(ch) + bf2f(cl);
        float dt  = softplusf_(fmaf(sxp[t * XPW_STRIDE], w, bb));
        float u = dt * xcv;
        float y = 0.f;
#pragma unroll
        for (int n = 0; n < NS; ++n) {
            float a = __expf(dt * Av[n]);
            h[n] = fmaf(a, h[n], u * sxp[t * XPW_STRIDE + 1 + n]);
            y = fmaf(h[n], sxp[t * XPW_STRIDE + 17 + n], y);
        }
        float out = fmaf(xcv, Dv, y) * (zv * sigmoidf_(zv));
        yhp[(size_t)t * DI] = f2bf_rn(out);
    }
}

extern "C" void kernel_launch(void* const* d_in, const int* in_sizes, int n_in,
                              void* d_out, int out_size, void* d_ws, size_t ws_size,
                              hipStream_t stream)
{
    (void)in_sizes; (void)n_in; (void)out_size;
    const float* x    = (const float*)d_in[0];
    const float* w1   = (const float*)d_in[1];
    const float* cw   = (const float*)d_in[2];
    const float* cb   = (const float*)d_in[3];
    const float* xpw  = (const float*)d_in[4];
    const float* dtw  = (const float*)d_in[5];
    const float* dtb  = (const float*)d_in[6];
    const float* alog = (const float*)d_in[7];
    const float* Dp   = (const float*)d_in[8];
    const float* w2   = (const float*)d_in[9];
    float* out = (float*)d_out;

    char* ws = (char*)d_ws;
    const size_t MB = 1024 * 1024;
    const size_t KB = 1024;
    if (ws_size < 81 * MB) return;

    // phase-1 overlay [0, 24MB): cast inputs for GEMM1
    unsigned short* x_hi  = (unsigned short*)(ws + 0);        // 4 MB
    unsigned short* x_lo  = (unsigned short*)(ws + 4 * MB);   // 4 MB
    unsigned short* w1_hi = (unsigned short*)(ws + 8 * MB);   // 8 MB
    unsigned short* w1_lo = (unsigned short*)(ws + 16 * MB);  // 8 MB
    // xproj-phase overlay (w1_lo dead after GEMM1):
    float* xp_part = (float*)(ws + 16 * MB);                  // 4 MB (8 x 2048 x 64 f32)
    // scan-phase overlay ([0,24MB) free: x/w1 dead; xp_part dead after xproj_reduce):
    unsigned short* y_hi  = (unsigned short*)(ws + 0);        // 8 MB
    float* h0    = (float*)(ws + 8 * MB);                     // 16 MB (2*64*2048*16 f32)
    float* sumdt = (float*)d_out;                             // 1 MB scratch inside d_out (dead window:
                                                              // written pass1, read pass2, overwritten by reduce4)
    // fixed region:
    float* xz = (float*)(ws + 24 * MB);                       // 32 MB
    float* c_part = (float*)(ws + 24 * MB);                   // 32 MB (GEMM2 split-K partials; xz dead by then)
    unsigned short* xc_hi = (unsigned short*)(ws + 56 * MB);  // 8 MB
    unsigned short* xc_lo = (unsigned short*)(ws + 64 * MB);  // 8 MB
    float* xp = (float*)(ws + 72 * MB);                       // 512 KB (2048 x 64)
    unsigned short* wp_hi = (unsigned short*)(ws + 72 * MB + 512 * KB);  // 256 KB
    unsigned short* wp_lo = (unsigned short*)(ws + 72 * MB + 768 * KB);  // 256 KB
    unsigned short* w2_hi = (unsigned short*)(ws + 73 * MB);  // 4 MB
    unsigned short* w2_lo = (unsigned short*)(ws + 77 * MB);  // 4 MB

    // fused casts (x, w1, w2, padded x_proj_w)
    {
        int total = XN4 + W1N4 + W2N4 + WPN4;
        cast_all_kernel<<<(total + 255) / 256, 256, 0, stream>>>(
            x, w1, w2, xpw, x_hi, x_lo, w1_hi, w1_lo, w2_hi, w2_lo, wp_hi, wp_lo);
    }

    // GEMM1 (mixed): xz[2048][4096] = x[2048][1024] . in_proj_w[4096][1024]^T
    // cols < 2048 (x_ssm): 2-term; cols >= 2048 (z gate): 3-term.
    {
        dim3 g(4096 / 128, 2048 / 128, 1);
        gemm3_bt<128, 128, true><<<g, 256, 0, stream>>>(x_hi, x_lo, w1_hi, w1_lo, xz, 2048, 4096, 1024, 1024, 2048);
    }

    conv_silu_kernel<<<(2048 * 512) / 256, 256, 0, stream>>>(xz, cw, cb, xc_hi, xc_lo);

    // x_proj via split-K MFMA GEMM (M=2048, N=64 padded, K=2048, SK=8)
    {
        dim3 g(1, 2048 / 64, 8);
        gemm3_xproj<<<g, 256, 0, stream>>>(xc_hi, xc_lo, wp_hi, wp_lo, xp_part);
        xproj_reduce<<<128, 256, 0, stream>>>(xp_part, xp);
    }

    {
        dim3 gs(DI / 256, NCH, B_);
        scan_pass1<<<gs, 256, 0, stream>>>(xc_hi, xc_lo, xp, dtw, dtb, alog, h0, sumdt);
        scan_pass2<<<(B_ * DI * NS) / 256, 256, 0, stream>>>(alog, sumdt, h0);
        scan_pass3<<<gs, 256, 0, stream>>>(xc_hi, xc_lo, xp, xz, dtw, dtb, alog, Dp, h0, y_hi);
    }

    // GEMM2 (2-term, y bf16-hi only): out[2048][1024] = y[2048][2048] . out_proj_w[1024][2048]^T
    // split-K=4 (KC=512) -> 512 blocks (2/CU), fp32 partials in c_part, then reduce.
    {
        dim3 g(1024 / 128, 2048 / 128, 4);
        gemm3_bt<128, 128, false><<<g, 256, 0, stream>>>(y_hi, nullptr, w2_hi, w2_lo, c_part, 2048, 1024, 2048, 512, 1 << 30);
        reduce4_kernel<<<(2048 * 1024 / 4 + 255) / 256, 256, 0, stream>>>(c_part, out, 2048 * 1024 / 4, 2048 * 1024 / 4);
    }
}

// Round 9
// 169.676 us; speedup vs baseline: 1.1413x; 1.0886x over previous
//
#include <hip/hip_runtime.h>
#include <hip/hip_bf16.h>
#include <math.h>

#define B_   2
#define L_   1024
#define DM   1024
#define DI   2048
#define NS   16
#define NPJ  33
#define XPW_STRIDE 64   // padded x_proj rows / xp row stride
#define NCH  64     // chunks
#define CHL  16     // chunk length

typedef __bf16 bf16x8 __attribute__((ext_vector_type(8)));
typedef float  f32x4  __attribute__((ext_vector_type(4)));

__device__ __forceinline__ unsigned short f2bf_rn(float x) {
    union { float f; unsigned u; } a; a.f = x;
    unsigned r = a.u + 0x7fffu + ((a.u >> 16) & 1u);
    return (unsigned short)(r >> 16);
}
__device__ __forceinline__ float bf2f(unsigned short h) {
    union { unsigned u; float f; } a; a.u = ((unsigned)h) << 16;
    return a.f;
}
__device__ __forceinline__ float sigmoidf_(float x) { return 1.f / (1.f + __expf(-x)); }
__device__ __forceinline__ float softplusf_(float x) {
    return x > 20.f ? x : log1pf(__expf(x));
}

#define GLDS(g, l) __builtin_amdgcn_global_load_lds( \
    (__attribute__((address_space(1))) void*)(g),    \
    (__attribute__((address_space(3))) void*)(l), 16, 0, 0)

// ---------------- fused cast ----------------
// x -> hi only (GEMM1 is 2-term: x_hi * (W1h+W1l));  w1 -> hi/lo pair;
// w2 -> hi only (GEMM2 is 1-term);  x_proj_w -> padded hi/lo pair.
#define XN4   524288          // 2048*1024/4
#define W1N4  1048576         // 4096*1024/4
#define W2N4  524288          // 1024*2048/4
#define WPN4  32768           // 64*2048/4
__global__ __launch_bounds__(256) void cast_all_kernel(
    const float* __restrict__ x, const float* __restrict__ w1,
    const float* __restrict__ w2, const float* __restrict__ xpw,
    unsigned short* __restrict__ xh,
    unsigned short* __restrict__ w1h, unsigned short* __restrict__ w1l,
    unsigned short* __restrict__ w2h,
    unsigned short* __restrict__ wph, unsigned short* __restrict__ wpl)
{
    int i = blockIdx.x * 256 + threadIdx.x;
    if (i < XN4) {
        float4 v = ((const float4*)x)[i];
        ushort4 H;
        H.x = f2bf_rn(v.x); H.y = f2bf_rn(v.y); H.z = f2bf_rn(v.z); H.w = f2bf_rn(v.w);
        ((ushort4*)xh)[i] = H;
    } else if (i < XN4 + W1N4) {
        int li = i - XN4;
        float4 v = ((const float4*)w1)[li];
        ushort4 H, L;
        H.x = f2bf_rn(v.x); L.x = f2bf_rn(v.x - bf2f(H.x));
        H.y = f2bf_rn(v.y); L.y = f2bf_rn(v.y - bf2f(H.y));
        H.z = f2bf_rn(v.z); L.z = f2bf_rn(v.z - bf2f(H.z));
        H.w = f2bf_rn(v.w); L.w = f2bf_rn(v.w - bf2f(H.w));
        ((ushort4*)w1h)[li] = H; ((ushort4*)w1l)[li] = L;
    } else if (i < XN4 + W1N4 + W2N4) {
        int li = i - (XN4 + W1N4);
        float4 v = ((const float4*)w2)[li];
        ushort4 H;
        H.x = f2bf_rn(v.x); H.y = f2bf_rn(v.y); H.z = f2bf_rn(v.z); H.w = f2bf_rn(v.w);
        ((ushort4*)w2h)[li] = H;
    } else if (i < XN4 + W1N4 + W2N4 + WPN4) {
        int li = i - (XN4 + W1N4 + W2N4);
        int j = li >> 9;
        float4 v = (j < NPJ) ? ((const float4*)xpw)[li] : make_float4(0.f, 0.f, 0.f, 0.f);
        ushort4 H, L;
        H.x = f2bf_rn(v.x); L.x = f2bf_rn(v.x - bf2f(H.x));
        H.y = f2bf_rn(v.y); L.y = f2bf_rn(v.y - bf2f(H.y));
        H.z = f2bf_rn(v.z); L.z = f2bf_rn(v.z - bf2f(H.z));
        H.w = f2bf_rn(v.w); L.w = f2bf_rn(v.w - bf2f(H.w));
        ((ushort4*)wph)[li] = H; ((ushort4*)wpl)[li] = L;
    }
}

// ---------------- split-bf16 GEMM: C[m][n] = sum_k A[m][k]*B[n][k] ----------------
// TERMS=2: Ah*Bh + Ah*Bl (B is a hi/lo pair).  TERMS=1: Ah*Bh only.
// Split-K: gridDim.z chunks of KC; partial z written to C + z*M*N.
// No XCD swizzle (R6: raised FETCH 41->70MB); no runtime term-branch (R8: broke scheduling).
template<int BM, int BN, int TERMS>
__global__ __launch_bounds__(256) void gemm_bt(
    const unsigned short* __restrict__ Ah,
    const unsigned short* __restrict__ Bh, const unsigned short* __restrict__ Bl,
    float* __restrict__ C, int M, int N, int K, int KC)
{
    constexpr int BK = 64;                 // 128 bytes per LDS row
    constexpr int FM = BM / 32;
    constexpr int FN = BN / 32;
    __shared__ alignas(16) char sAh[BM * BK * 2];
    __shared__ alignas(16) char sBh[BN * BK * 2];
    __shared__ alignas(16) char sBl[TERMS == 2 ? BN * BK * 2 : 16];

    const int tid  = threadIdx.x;
    const int lane = tid & 63;
    const int wave = tid >> 6;
    const int wm = wave >> 1, wn = wave & 1;
    const int m0 = blockIdx.y * BM, n0 = blockIdx.x * BN;
    const int k0 = blockIdx.z * KC;

    f32x4 acc[FM][FN];
#pragma unroll
    for (int i = 0; i < FM; ++i)
#pragma unroll
        for (int j = 0; j < FN; ++j)
            acc[i][j] = (f32x4){0.f, 0.f, 0.f, 0.f};

    for (int kt = k0; kt < k0 + KC; kt += BK) {
#pragma unroll
        for (int iss = 0; iss < BM / 32; ++iss) {
            int o  = (iss * 256 + tid) * 16;
            int r  = o >> 7;
            int cb = (o & 127) ^ ((r & 7) << 4);
            size_t goff = (size_t)(m0 + r) * K + kt + (cb >> 1);
            GLDS(Ah + goff, sAh + iss * 4096 + wave * 1024);
        }
#pragma unroll
        for (int iss = 0; iss < BN / 32; ++iss) {
            int o  = (iss * 256 + tid) * 16;
            int r  = o >> 7;
            int cb = (o & 127) ^ ((r & 7) << 4);
            size_t goff = (size_t)(n0 + r) * K + kt + (cb >> 1);
            GLDS(Bh + goff, sBh + iss * 4096 + wave * 1024);
            if (TERMS == 2) GLDS(Bl + goff, sBl + iss * 4096 + wave * 1024);
        }
        __syncthreads();

#pragma unroll
        for (int kk = 0; kk < 2; ++kk) {
            const int ke = kk * 32 + (lane >> 4) * 8;
            bf16x8 ah[FM], bh[FN], bl[FN];
#pragma unroll
            for (int i = 0; i < FM; ++i) {
                int r = wm * (BM / 2) + i * 16 + (lane & 15);
                int off = (r * 128 + ke * 2) ^ ((r & 7) << 4);
                ah[i] = *(const bf16x8*)(sAh + off);
            }
#pragma unroll
            for (int j = 0; j < FN; ++j) {
                int r = wn * (BN / 2) + j * 16 + (lane & 15);
                int off = (r * 128 + ke * 2) ^ ((r & 7) << 4);
                bh[j] = *(const bf16x8*)(sBh + off);
                if (TERMS == 2) bl[j] = *(const bf16x8*)(sBl + off);
            }
#pragma unroll
            for (int i = 0; i < FM; ++i)
#pragma unroll
                for (int j = 0; j < FN; ++j) {
                    acc[i][j] = __builtin_amdgcn_mfma_f32_16x16x32_bf16(ah[i], bh[j], acc[i][j], 0, 0, 0);
                    if (TERMS == 2) acc[i][j] = __builtin_amdgcn_mfma_f32_16x16x32_bf16(ah[i], bl[j], acc[i][j], 0, 0, 0);
                }
        }
        __syncthreads();
    }

    float* Cz = C + (size_t)blockIdx.z * M * N;
#pragma unroll
    for (int i = 0; i < FM; ++i)
#pragma unroll
        for (int j = 0; j < FN; ++j) {
            int row = m0 + wm * (BM / 2) + i * 16 + (lane >> 4) * 4;
            int col = n0 + wn * (BN / 2) + j * 16 + (lane & 15);
            float* p = Cz + (size_t)row * N + col;
#pragma unroll
            for (int q = 0; q < 4; ++q) p[(size_t)q * N] = acc[i][j][q];
        }
}

// ---------------- reduce 4 split-K partials ----------------
__global__ __launch_bounds__(256) void reduce4_kernel(
    const float* __restrict__ part, float* __restrict__ out, int n4, int stride4)
{
    int i = blockIdx.x * 256 + threadIdx.x;
    if (i >= n4) return;
    const float4* p = (const float4*)part;
    float4 s = p[i];
#pragma unroll
    for (int z = 1; z < 4; ++z) {
        float4 v = p[(size_t)z * stride4 + i];
        s.x += v.x; s.y += v.y; s.z += v.z; s.w += v.w;
    }
    ((float4*)out)[i] = s;
}

// ---------------- x_proj split-K GEMM: part[z][m][n] = sum_{k in chunk z} xc[m][k]*Wp[n][k] ----------------
// 3-term (xc hi/lo x Wp hi/lo) — dt path is precision-sensitive; keep full.
__global__ __launch_bounds__(256) void gemm3_xproj(
    const unsigned short* __restrict__ Ah, const unsigned short* __restrict__ Al,
    const unsigned short* __restrict__ Bh, const unsigned short* __restrict__ Bl,
    float* __restrict__ part)
{
    constexpr int BM = 64, BN = 64, BK = 64, KTOT = 2048, KC = 256;
    __shared__ alignas(16) char sAh[BM * 128];
    __shared__ alignas(16) char sAl[BM * 128];
    __shared__ alignas(16) char sBh[BN * 128];
    __shared__ alignas(16) char sBl[BN * 128];

    const int tid  = threadIdx.x;
    const int lane = tid & 63;
    const int wave = tid >> 6;
    const int wm = wave >> 1, wn = wave & 1;
    const int m0 = blockIdx.y * BM;
    const int kt0 = blockIdx.z * KC;

    f32x4 acc[2][2];
#pragma unroll
    for (int i = 0; i < 2; ++i)
#pragma unroll
        for (int j = 0; j < 2; ++j) acc[i][j] = (f32x4){0.f, 0.f, 0.f, 0.f};

    for (int kt = 0; kt < KC; kt += BK) {
#pragma unroll
        for (int iss = 0; iss < 2; ++iss) {
            int o  = (iss * 256 + tid) * 16;
            int r  = o >> 7;
            int cb = (o & 127) ^ ((r & 7) << 4);
            size_t ga = (size_t)(m0 + r) * KTOT + kt0 + kt + (cb >> 1);
            GLDS(Ah + ga, sAh + iss * 4096 + wave * 1024);
            GLDS(Al + ga, sAl + iss * 4096 + wave * 1024);
            size_t gb = (size_t)r * KTOT + kt0 + kt + (cb >> 1);
            GLDS(Bh + gb, sBh + iss * 4096 + wave * 1024);
            GLDS(Bl + gb, sBl + iss * 4096 + wave * 1024);
        }
        __syncthreads();

#pragma unroll
        for (int kk = 0; kk < 2; ++kk) {
            const int ke = kk * 32 + (lane >> 4) * 8;
            bf16x8 ah[2], al[2], bh[2], bl[2];
#pragma unroll
            for (int i = 0; i < 2; ++i) {
                int r = wm * 32 + i * 16 + (lane & 15);
                int off = (r * 128 + ke * 2) ^ ((r & 7) << 4);
                ah[i] = *(const bf16x8*)(sAh + off);
                al[i] = *(const bf16x8*)(sAl + off);
            }
#pragma unroll
            for (int j = 0; j < 2; ++j) {
                int r = wn * 32 + j * 16 + (lane & 15);
                int off = (r * 128 + ke * 2) ^ ((r & 7) << 4);
                bh[j] = *(const bf16x8*)(sBh + off);
                bl[j] = *(const bf16x8*)(sBl + off);
            }
#pragma unroll
            for (int i = 0; i < 2; ++i)
#pragma unroll
                for (int j = 0; j < 2; ++j) {
                    acc[i][j] = __builtin_amdgcn_mfma_f32_16x16x32_bf16(ah[i], bh[j], acc[i][j], 0, 0, 0);
                    acc[i][j] = __builtin_amdgcn_mfma_f32_16x16x32_bf16(ah[i], bl[j], acc[i][j], 0, 0, 0);
                    acc[i][j] = __builtin_amdgcn_mfma_f32_16x16x32_bf16(al[i], bh[j], acc[i][j], 0, 0, 0);
                }
        }
        __syncthreads();
    }

    float* Cp = part + (size_t)blockIdx.z * 2048 * XPW_STRIDE;
#pragma unroll
    for (int i = 0; i < 2; ++i)
#pragma unroll
        for (int j = 0; j < 2; ++j) {
            int row = m0 + wm * 32 + i * 16 + (lane >> 4) * 4;
            int col = wn * 32 + j * 16 + (lane & 15);
            float* p = Cp + (size_t)row * XPW_STRIDE + col;
#pragma unroll
            for (int q = 0; q < 4; ++q) p[(size_t)q * XPW_STRIDE] = acc[i][j][q];
        }
}

// ---------------- reduce split-K partials: xp = sum_z part[z] ----------------
__global__ __launch_bounds__(256) void xproj_reduce(
    const float* __restrict__ part, float* __restrict__ xp)
{
    int i = blockIdx.x * 256 + threadIdx.x;   // over 2048*64/4 = 32768 float4
    const float4* p = (const float4*)part;
    float4 s = p[i];
#pragma unroll
    for (int z = 1; z < 8; ++z) {
        float4 v = p[(size_t)z * 32768 + i];
        s.x += v.x; s.y += v.y; s.z += v.z; s.w += v.w;
    }
    ((float4*)xp)[i] = s;
}

// ---------------- causal conv(4) + silu -> hi/lo bf16 ----------------
__global__ __launch_bounds__(256) void conv_silu_kernel(
    const float* __restrict__ xz, const float* __restrict__ cw,
    const float* __restrict__ cb, unsigned short* __restrict__ xch,
    unsigned short* __restrict__ xcl)
{
    int gid = blockIdx.x * 256 + threadIdx.x;   // 2048 rows * 512 vec4
    int m  = gid >> 9;
    int dv = (gid & 511) << 2;
    int t  = m & (L_ - 1);
    const float* base = xz + (size_t)m * (2 * DI) + dv;
    float4 s  = *(const float4*)(cb + dv);
    float4 w0 = *(const float4*)(cw + (dv + 0) * 4);
    float4 w1 = *(const float4*)(cw + (dv + 1) * 4);
    float4 w2 = *(const float4*)(cw + (dv + 2) * 4);
    float4 w3 = *(const float4*)(cw + (dv + 3) * 4);
    float4 z4 = make_float4(0.f, 0.f, 0.f, 0.f);
    float4 x3 = *(const float4*)(base);
    float4 x2 = (t >= 1) ? *(const float4*)(base - 1 * (2 * DI)) : z4;
    float4 x1 = (t >= 2) ? *(const float4*)(base - 2 * (2 * DI)) : z4;
    float4 x0 = (t >= 3) ? *(const float4*)(base - 3 * (2 * DI)) : z4;
    float r0 = s.x + w0.x * x0.x + w0.y * x1.x + w0.z * x2.x + w0.w * x3.x;
    float r1 = s.y + w1.x * x0.y + w1.y * x1.y + w1.z * x2.y + w1.w * x3.y;
    float r2 = s.z + w2.x * x0.z + w2.y * x1.z + w2.z * x2.z + w2.w * x3.z;
    float r3 = s.w + w3.x * x0.w + w3.y * x1.w + w3.z * x2.w + w3.w * x3.w;
    float4 o;
    o.x = r0 * sigmoidf_(r0);
    o.y = r1 * sigmoidf_(r1);
    o.z = r2 * sigmoidf_(r2);
    o.w = r3 * sigmoidf_(r3);
    ushort4 H, L;
    H.x = f2bf_rn(o.x); L.x = f2bf_rn(o.x - bf2f(H.x));
    H.y = f2bf_rn(o.y); L.y = f2bf_rn(o.y - bf2f(H.y));
    H.z = f2bf_rn(o.z); L.z = f2bf_rn(o.z - bf2f(H.z));
    H.w = f2bf_rn(o.w); L.w = f2bf_rn(o.w - bf2f(H.w));
    *(ushort4*)(xch + (size_t)m * DI + dv) = H;
    *(ushort4*)(xcl + (size_t)m * DI + dv) = L;
}

// ---------------- scan pass 1: per-chunk local scan (h_in = 0) + sum(dt) ----------------
__global__ __launch_bounds__(256) void scan_pass1(
    const unsigned short* __restrict__ xch, const unsigned short* __restrict__ xcl,
    const float* __restrict__ xp,
    const float* __restrict__ dtw, const float* __restrict__ dtb,
    const float* __restrict__ A_log, float* __restrict__ h0, float* __restrict__ sumdt)
{
    const int b = blockIdx.z, c = blockIdx.y;
    const int tid = threadIdx.x;
    const int d = blockIdx.x * 256 + tid;
    __shared__ float sxp[CHL * XPW_STRIDE];
    const float* xpsrc = xp + (size_t)(b * L_ + c * CHL) * XPW_STRIDE;
    for (int i = tid; i < CHL * XPW_STRIDE / 4; i += 256)
        ((float4*)sxp)[i] = ((const float4*)xpsrc)[i];
    __syncthreads();

    float Av[NS];
#pragma unroll
    for (int n = 0; n < NS; ++n) Av[n] = -__expf(A_log[(size_t)d * NS + n]);
    const float w = dtw[d], bb = dtb[d];
    float h[NS];
#pragma unroll
    for (int n = 0; n < NS; ++n) h[n] = 0.f;
    float sd = 0.f;
    size_t off = (size_t)(b * L_ + c * CHL) * DI + d;

    unsigned short nh = xch[off], nl = xcl[off];
    for (int t = 0; t < CHL; ++t) {
        unsigned short ch = nh, cl = nl;
        nh = xch[off + DI]; nl = xcl[off + DI];    // prefetch t+1 (last iter overruns, value unused)
        off += DI;
        float xcv = bf2f(ch) + bf2f(cl);
        float dt  = softplusf_(fmaf(sxp[t * XPW_STRIDE], w, bb));
        sd += dt;
        float u = dt * xcv;
#pragma unroll
        for (int n = 0; n < NS; ++n) {
            float a = __expf(dt * Av[n]);
            h[n] = fmaf(a, h[n], u * sxp[t * XPW_STRIDE + 1 + n]);
        }
    }
    float* hp = h0 + ((size_t)(b * NCH + c) * DI + d) * NS;
#pragma unroll
    for (int n = 0; n < NS; n += 4)
        *(float4*)(hp + n) = make_float4(h[n], h[n + 1], h[n + 2], h[n + 3]);
    sumdt[(size_t)(b * NCH + c) * DI + d] = sd;
}

// ---------------- scan pass 2: chunk-level prefix (in place: h0 becomes h_in) ----------------
// Batched: 16 independent loads + exps per group, serial chain is fma-only.
__global__ __launch_bounds__(256) void scan_pass2(
    const float* __restrict__ A_log, const float* __restrict__ sumdt, float* __restrict__ h0)
{
    int gid = blockIdx.x * 256 + threadIdx.x;   // B_*DI*NS = 65536
    int b = gid >> 15;
    int r = gid & 32767;
    int d = r >> 4, n = r & 15;
    float An = -__expf(A_log[(size_t)d * NS + n]);
    float h = 0.f;
    for (int cb = 0; cb < NCH; cb += 16) {
        float hl[16], e[16];
#pragma unroll
        for (int j = 0; j < 16; ++j) {
            size_t ci = (size_t)(b * NCH + cb + j) * DI + d;
            hl[j] = h0[ci * NS + n];
            e[j]  = An * sumdt[ci];
        }
#pragma unroll
        for (int j = 0; j < 16; ++j) e[j] = __expf(e[j]);
#pragma unroll
        for (int j = 0; j < 16; ++j) {
            size_t ci = (size_t)(b * NCH + cb + j) * DI + d;
            h0[ci * NS + n] = h;
            h = fmaf(e[j], h, hl[j]);
        }
    }
}

// ---------------- scan pass 3: replay with h_in, fuse y, D-skip, silu(z), bf16 ----------------
__global__ __launch_bounds__(256) void scan_pass3(
    const unsigned short* __restrict__ xch, const unsigned short* __restrict__ xcl,
    const float* __restrict__ xp, const float* __restrict__ xz,
    const float* __restrict__ dtw, const float* __restrict__ dtb,
    const float* __restrict__ A_log, const float* __restrict__ Dp,
    const float* __restrict__ hin,
    unsigned short* __restrict__ yh)
{
    const int b = blockIdx.z, c = blockIdx.y;
    const int tid = threadIdx.x;
    const int d = blockIdx.x * 256 + tid;
    __shared__ float sxp[CHL * XPW_STRIDE];
    const float* xpsrc = xp + (size_t)(b * L_ + c * CHL) * XPW_STRIDE;
    for (int i = tid; i < CHL * XPW_STRIDE / 4; i += 256)
        ((float4*)sxp)[i] = ((const float4*)xpsrc)[i];
    __syncthreads();

    float Av[NS];
#pragma unroll
    for (int n = 0; n < NS; ++n) Av[n] = -__expf(A_log[(size_t)d * NS + n]);
    const float w = dtw[d], bb = dtb[d], Dv = Dp[d];
    float h[NS];
    const float* hp = hin + ((size_t)(b * NCH + c) * DI + d) * NS;
#pragma unroll
    for (int n = 0; n < NS; n += 4) {
        float4 v = *(const float4*)(hp + n);
        h[n] = v.x; h[n + 1] = v.y; h[n + 2] = v.z; h[n + 3] = v.w;
    }
    size_t off = (size_t)(b * L_ + c * CHL) * DI + d;
    const float* zp  = xz + (size_t)(b * L_ + c * CHL) * (2 * DI) + DI + d;
    unsigned short* yhp = yh + off;

    unsigned short nh = xch[off], nl = xcl[off];
    float nz = zp[0];
    for (int t = 0; t < CHL; ++t) {
        unsigned short ch = nh, cl = nl;
        float zv = nz;
        nh = xch[off + DI]; nl = xcl[off + DI];            // prefetch (overrun on last iter, unused)
        nz = zp[(size_t)(t + 1) * (2 * DI)];
        off += DI;
        float xcv = bf2f(ch) + bf2f(cl);
        float dt  = softplusf_(fmaf(sxp[t * XPW_STRIDE], w, bb));
        float u = dt * xcv;
        float y = 0.f;
#pragma unroll
        for (int n = 0; n < NS; ++n) {
            float a = __expf(dt * Av[n]);
            h[n] = fmaf(a, h[n], u * sxp[t * XPW_STRIDE + 1 + n]);
            y = fmaf(h[n], sxp[t * XPW_STRIDE + 17 + n], y);
        }
        float out = fmaf(xcv, Dv, y) * (zv * sigmoidf_(zv));
        yhp[(size_t)t * DI] = f2bf_rn(out);
    }
}

extern "C" void kernel_launch(void* const* d_in, const int* in_sizes, int n_in,
                              void* d_out, int out_size, void* d_ws, size_t ws_size,
                              hipStream_t stream)
{
    (void)in_sizes; (void)n_in; (void)out_size;
    const float* x    = (const float*)d_in[0];
    const float* w1   = (const float*)d_in[1];
    const float* cw   = (const float*)d_in[2];
    const float* cb   = (const float*)d_in[3];
    const float* xpw  = (const float*)d_in[4];
    const float* dtw  = (const float*)d_in[5];
    const float* dtb  = (const float*)d_in[6];
    const float* alog = (const float*)d_in[7];
    const float* Dp   = (const float*)d_in[8];
    const float* w2   = (const float*)d_in[9];
    float* out = (float*)d_out;

    char* ws = (char*)d_ws;
    const size_t MB = 1024 * 1024;
    const size_t KB = 1024;
    if (ws_size < 81 * MB) return;

    // phase-1 overlay [0, 24MB): cast inputs for GEMM1
    unsigned short* x_hi  = (unsigned short*)(ws + 0);        // 4 MB
    unsigned short* w1_hi = (unsigned short*)(ws + 8 * MB);   // 8 MB
    unsigned short* w1_lo = (unsigned short*)(ws + 16 * MB);  // 8 MB
    // xproj-phase overlay (w1_lo dead after GEMM1):
    float* xp_part = (float*)(ws + 16 * MB);                  // 4 MB (8 x 2048 x 64 f32)
    // scan-phase overlay ([0,24MB) free: x/w1 dead; xp_part dead after xproj_reduce):
    unsigned short* y_hi  = (unsigned short*)(ws + 0);        // 8 MB
    float* h0    = (float*)(ws + 8 * MB);                     // 16 MB (2*64*2048*16 f32)
    float* sumdt = (float*)d_out;                             // 1 MB scratch inside d_out (dead window:
                                                              // written pass1, read pass2, overwritten by reduce4)
    // fixed region:
    float* xz = (float*)(ws + 24 * MB);                       // 32 MB
    float* c_part = (float*)(ws + 24 * MB);                   // 32 MB (GEMM2 split-K partials; xz dead by then)
    unsigned short* xc_hi = (unsigned short*)(ws + 56 * MB);  // 8 MB
    unsigned short* xc_lo = (unsigned short*)(ws + 64 * MB);  // 8 MB
    float* xp = (float*)(ws + 72 * MB);                       // 512 KB (2048 x 64)
    unsigned short* wp_hi = (unsigned short*)(ws + 72 * MB + 512 * KB);  // 256 KB
    unsigned short* wp_lo = (unsigned short*)(ws + 72 * MB + 768 * KB);  // 256 KB
    unsigned short* w2_hi = (unsigned short*)(ws + 73 * MB);  // 4 MB
    unsigned short* w2_lo = (unsigned short*)(ws + 77 * MB);  // 4 MB (unused this round)
    (void)w2_lo;

    // fused casts (x hi-only, w1 pair, w2 hi-only, padded x_proj_w pair)
    {
        int total = XN4 + W1N4 + W2N4 + WPN4;
        cast_all_kernel<<<(total + 255) / 256, 256, 0, stream>>>(
            x, w1, w2, xpw, x_hi, w1_hi, w1_lo, w2_hi, wp_hi, wp_lo);
    }

    // GEMM1 (2-term: x_hi . (W1h + W1l)): xz[2048][4096]
    {
        dim3 g(4096 / 128, 2048 / 128, 1);
        gemm_bt<128, 128, 2><<<g, 256, 0, stream>>>(x_hi, w1_hi, w1_lo, xz, 2048, 4096, 1024, 1024);
    }

    conv_silu_kernel<<<(2048 * 512) / 256, 256, 0, stream>>>(xz, cw, cb, xc_hi, xc_lo);

    // x_proj via split-K MFMA GEMM (M=2048, N=64 padded, K=2048, SK=8), 3-term
    {
        dim3 g(1, 2048 / 64, 8);
        gemm3_xproj<<<g, 256, 0, stream>>>(xc_hi, xc_lo, wp_hi, wp_lo, xp_part);
        xproj_reduce<<<128, 256, 0, stream>>>(xp_part, xp);
    }

    {
        dim3 gs(DI / 256, NCH, B_);
        scan_pass1<<<gs, 256, 0, stream>>>(xc_hi, xc_lo, xp, dtw, dtb, alog, h0, sumdt);
        scan_pass2<<<(B_ * DI * NS) / 256, 256, 0, stream>>>(alog, sumdt, h0);
        scan_pass3<<<gs, 256, 0, stream>>>(xc_hi, xc_lo, xp, xz, dtw, dtb, alog, Dp, h0, y_hi);
    }

    // GEMM2 (1-term: y_hi . W2h): out[2048][1024]
    // split-K=4 (KC=512) -> 512 blocks (2/CU), fp32 partials in c_part, then reduce.
    {
        dim3 g(1024 / 128, 2048 / 128, 4);
        gemm_bt<128, 128, 1><<<g, 256, 0, stream>>>(y_hi, w2_hi, nullptr, c_part, 2048, 1024, 2048, 512);
        reduce4_kernel<<<(2048 * 1024 / 4 + 255) / 256, 256, 0, stream>>>(c_part, out, 2048 * 1024 / 4, 2048 * 1024 / 4);
    }
}